// Round 4
// baseline (575.652 us; speedup 1.0000x reference)
//
#include <hip/hip_runtime.h>
#include <stdint.h>

#define N_ROWS 16384
#define M_ROWS 16384
#define KDIM   512
#define BM 128          // 2 waves x 64 rows
#define BN 128
#define BK 128          // phases per bt = KDIM/BK = 4
#define NCHUNK 8
#define CHUNK_ROWS (M_ROWS / NCHUNK)      // 2048
#define BT_PER_CHUNK (CHUNK_ROWS / BN)    // 16

typedef _Float16 half8 __attribute__((ext_vector_type(8)));
typedef float floatx4 __attribute__((ext_vector_type(4)));

__device__ __forceinline__ void async_ld16(const _Float16* g, _Float16* l) {
  __builtin_amdgcn_global_load_lds(
      (const __attribute__((address_space(1))) void*)g,
      (__attribute__((address_space(3))) void*)l, 16, 0, 0);
}

// Kernel 1: fp32 -> f16 + per-row squared norms. One wave per row.
__global__ void conv_kernel(const float* __restrict__ A, const float* __restrict__ B,
                            _Float16* __restrict__ Ah, _Float16* __restrict__ Bh,
                            float* __restrict__ sq1, float* __restrict__ sq2) {
  const int lane = threadIdx.x & 63;
  const int wv = threadIdx.x >> 6;
  int row = blockIdx.x * 4 + wv;
  const float* src;
  _Float16* dst;
  float* sq;
  if (row < N_ROWS) {
    src = A + (size_t)row * KDIM;
    dst = Ah + (size_t)row * KDIM;
    sq = sq1 + row;
  } else {
    int r = row - N_ROWS;
    src = B + (size_t)r * KDIM;
    dst = Bh + (size_t)r * KDIM;
    sq = sq2 + r;
  }
  const float4* s4 = (const float4*)src;
  uint2* d2 = (uint2*)dst;
  float s = 0.f;
  #pragma unroll
  for (int h = 0; h < 2; h++) {
    float4 v = s4[lane + h * 64];
    union { _Float16 hh[4]; uint2 u; } pk;
    pk.hh[0] = (_Float16)v.x; pk.hh[1] = (_Float16)v.y;
    pk.hh[2] = (_Float16)v.z; pk.hh[3] = (_Float16)v.w;
    d2[lane + h * 64] = pk.u;
    s += v.x * v.x + v.y * v.y + v.z * v.z + v.w * v.w;
  }
  #pragma unroll
  for (int off = 32; off; off >>= 1) s += __shfl_down(s, off, 64);
  if (lane == 0) *sq = s;
}

// Kernel 2: fused GEMM + running-min.
// 2 waves/block, 64 A-rows per wave held fully in registers (areg[4][16], 256
// VGPRs), full K=512. Only B streams through LDS: double-buffered 2 x 32KB
// (BK=128), XOR-swizzled (row r, 16B-slot s holds global chunk s ^ (r&15)) so
// ds_read_b128 runs at the 8-cycle b128 minimum, conflict-free.
// FLOP per LDS byte = 64 (vs 32 in R3) -> MFMA-bound 2:1 over the LDS pipe.
// 1-D grid, chunk = bid & 7 pins each 2MB B-chunk to one XCD's L2.
__global__ void __launch_bounds__(128, 1)
gemm_min_kernel(const _Float16* __restrict__ Ah, const _Float16* __restrict__ Bh,
                const float* __restrict__ sq2, float* __restrict__ ws_min) {
  __shared__ __align__(16) _Float16 lsB[2][BN * BK];   // 2 x 32 KB

  const int tid = threadIdx.x;
  const int lane = tid & 63;
  const int wv = tid >> 6;       // 0..1, owns A rows [wv*64, wv*64+64)
  const int fr = lane & 15;
  const int kg = lane >> 4;      // 0..3

  const int bid = blockIdx.x;
  const int chunk = bid & 7;     // == XCD under bid%8 round-robin
  const int rowBase = (bid >> 3) * BM;
  const int colBase0 = chunk * CHUNK_ROWS;

  // Staging geometry: slot = wv*16+c covers 4 B-rows (256 B each).
  const int r_st = lane >> 4;    // row-in-slot 0..3
  const int s_st = lane & 15;    // 16B-chunk-in-row 0..15

  // ---- Persistent A fragments: areg[i][kf] covers row wv*64 + i*16 + fr,
  // k = kf*32 + kg*8 .. +8.  4 x 16 = 64 half8 = 256 VGPRs.
  half8 areg[4][16];
  {
    const _Float16* abase = Ah + (size_t)(rowBase + wv * 64 + fr) * KDIM + kg * 8;
    #pragma unroll
    for (int i = 0; i < 4; i++)
      #pragma unroll
      for (int kf = 0; kf < 16; kf++)
        areg[i][kf] = *(const half8*)(abase + (size_t)i * 16 * KDIM + kf * 32);
  }

  float runmin[4][4];
  #pragma unroll
  for (int i = 0; i < 4; i++)
    #pragma unroll
    for (int r4 = 0; r4 < 4; r4++) runmin[i][r4] = 3.0e38f;

  // Stage one 128-col x 128-k phase (32 KB): 16 calls/wave.
  #define STAGE_B(buf, cb, kbase_)                                            \
    {                                                                         \
      _Pragma("unroll")                                                       \
      for (int c = 0; c < 16; ++c) {                                          \
        const int slot = wv * 16 + c;                                         \
        const int col = slot * 4 + r_st;                                      \
        const int key = ((slot & 3) << 2) + r_st;                             \
        const int kofs = (s_st ^ key) << 3;                                   \
        async_ld16(Bh + (size_t)((cb) + col) * KDIM + (kbase_) + kofs,        \
                   (buf) + (slot << 9));                                      \
      }                                                                       \
    }

  // Prologue: stage phase 0 of bt 0 into buf 0.
  STAGE_B(lsB[0], colBase0, 0)
  __syncthreads();

  for (int bt = 0; bt < BT_PER_CHUNK; ++bt) {
    const int colBase = colBase0 + bt * BN;
    floatx4 acc[4][8];
    #pragma unroll
    for (int i = 0; i < 4; i++)
      #pragma unroll
      for (int j = 0; j < 8; j++) acc[i][j] = (floatx4){0.f, 0.f, 0.f, 0.f};

    #pragma unroll
    for (int kb = 0; kb < 4; ++kb) {
      const _Float16* cur = lsB[kb & 1];
      // Prefetch next phase into the other buffer (hides under the MFMAs).
      if (kb < 3) {
        STAGE_B(lsB[(kb + 1) & 1], colBase, (kb + 1) * BK)
      } else if (bt + 1 < BT_PER_CHUNK) {
        STAGE_B(lsB[0], colBase + BN, 0)
      }
      // Compute phase kb: 128 MFMAs/wave from cur + A registers.
      #pragma unroll
      for (int ks = 0; ks < 4; ++ks) {
        #pragma unroll
        for (int j = 0; j < 8; j++) {
          const int c16 = (ks << 2) + kg;            // wanted 16B chunk 0..15
          half8 bf = *(const half8*)(cur + (j * 16 + fr) * BK + ((c16 ^ fr) << 3));
          #pragma unroll
          for (int i = 0; i < 4; i++)
            acc[i][j] = __builtin_amdgcn_mfma_f32_16x16x32_f16(
                areg[i][(kb << 2) + ks], bf, acc[i][j], 0, 0, 0);
        }
      }
      __syncthreads();  // drains prefetch + publishes next buffer
    }

    // Epilogue: cand = sq2[col] - 2*inner -> per-row running min.
    // C frag: col = j*16 + fr, row = wv*64 + i*16 + kg*4 + reg.
    #pragma unroll
    for (int j = 0; j < 8; j++) {
      const float s2 = sq2[colBase + j * 16 + fr];
      #pragma unroll
      for (int i = 0; i < 4; i++)
        #pragma unroll
        for (int r4 = 0; r4 < 4; r4++) {
          const float cand = fmaf(-2.f, acc[i][j][r4], s2);
          runmin[i][r4] = fminf(runmin[i][r4], cand);
        }
    }
  }

  // Min over the 16 columns per lane row-group: butterfly on lane bits 0..3.
  #pragma unroll
  for (int i = 0; i < 4; i++)
    #pragma unroll
    for (int r4 = 0; r4 < 4; r4++) {
      float v = runmin[i][r4];
      v = fminf(v, __shfl_xor(v, 1, 64));
      v = fminf(v, __shfl_xor(v, 2, 64));
      v = fminf(v, __shfl_xor(v, 4, 64));
      v = fminf(v, __shfl_xor(v, 8, 64));
      runmin[i][r4] = v;
    }

  // Waves own distinct rows -> direct write.
  if (fr == 0) {
    #pragma unroll
    for (int i = 0; i < 4; i++)
      #pragma unroll
      for (int r4 = 0; r4 < 4; r4++) {
        const int lrow = wv * 64 + i * 16 + kg * 4 + r4;
        ws_min[(size_t)chunk * N_ROWS + rowBase + lrow] = runmin[i][r4];
      }
  }
}

// Kernel 3a: per-row min across chunks + sqrt/relu, 64-block partial sums.
__global__ void partial_kernel(const float* __restrict__ ws_min,
                               const float* __restrict__ sq1,
                               float* __restrict__ part) {
  const int r = blockIdx.x * 256 + threadIdx.x;   // 64*256 = 16384 rows
  float m = ws_min[r];
  #pragma unroll
  for (int c = 1; c < NCHUNK; c++) m = fminf(m, ws_min[(size_t)c * N_ROWS + r]);
  float d2 = sq1[r] + m;
  d2 = d2 > 0.f ? d2 : 0.f;
  float v = sqrtf(d2) - 0.1f;
  float s = v > 0.f ? v : 0.f;
  #pragma unroll
  for (int off = 32; off; off >>= 1) s += __shfl_down(s, off, 64);
  __shared__ float ps[4];
  if ((threadIdx.x & 63) == 0) ps[threadIdx.x >> 6] = s;
  __syncthreads();
  if (threadIdx.x == 0) part[blockIdx.x] = ps[0] + ps[1] + ps[2] + ps[3];
}

// Kernel 3b: combine 64 partials.
__global__ void final_kernel(const float* __restrict__ part, float* __restrict__ out) {
  float s = part[threadIdx.x];
  #pragma unroll
  for (int off = 32; off; off >>= 1) s += __shfl_down(s, off, 64);
  if (threadIdx.x == 0) out[0] = s / (float)N_ROWS;
}

extern "C" void kernel_launch(void* const* d_in, const int* in_sizes, int n_in,
                              void* d_out, int out_size, void* d_ws, size_t ws_size,
                              hipStream_t stream) {
  const float* A = (const float*)d_in[0];
  const float* B = (const float*)d_in[1];
  char* ws = (char*)d_ws;
  const size_t halfBytes = (size_t)N_ROWS * KDIM * 2;  // 16 MiB each
  _Float16* Ah = (_Float16*)ws;
  _Float16* Bh = (_Float16*)(ws + halfBytes);
  float* sq1 = (float*)(ws + 2 * halfBytes);
  float* sq2 = sq1 + N_ROWS;
  float* ws_min = sq2 + M_ROWS;
  float* part = ws_min + (size_t)NCHUNK * N_ROWS;

  conv_kernel<<<dim3((N_ROWS + M_ROWS) / 4), dim3(256), 0, stream>>>(A, B, Ah, Bh, sq1, sq2);
  gemm_min_kernel<<<dim3((N_ROWS / BM) * NCHUNK), dim3(128), 0, stream>>>(Ah, Bh, sq2, ws_min);
  partial_kernel<<<dim3(64), dim3(256), 0, stream>>>(ws_min, sq1, part);
  final_kernel<<<dim3(1), dim3(64), 0, stream>>>(part, (float*)d_out);
}

// Round 5
// 212.302 us; speedup vs baseline: 2.7115x; 2.7115x over previous
//
#include <hip/hip_runtime.h>
#include <stdint.h>

#define N_ROWS 16384
#define M_ROWS 16384
#define KDIM   512
#define BM 128           // 2 waves x 64 rows
#define BNT 64           // cols per bt tile
#define BKP 128          // k per phase (one MFMA K)
#define NCHUNK 8
#define CHUNK_ROWS (M_ROWS / NCHUNK)       // 2048
#define BT_PER_CHUNK (CHUNK_ROWS / BNT)    // 32

typedef int intx4 __attribute__((ext_vector_type(4)));
typedef int intx8 __attribute__((ext_vector_type(8)));
typedef float floatx4 __attribute__((ext_vector_type(4)));

#define UNIT_SCALE 0x7F7F7F7F  // E8M0 exponent 127 -> 2^0 = 1.0 in every byte

__device__ __forceinline__ void async_ld16(const uint8_t* g, uint8_t* l) {
  __builtin_amdgcn_global_load_lds(
      (const __attribute__((address_space(1))) void*)g,
      (__attribute__((address_space(3))) void*)l, 16, 0, 0);
}

// Kernel 1: fp32 -> fp8 e4m3 (unit scale; |x|<=~5.5 fits e4m3 range 448)
// + per-row squared norms in exact fp32. One wave per row.
__global__ void conv_kernel(const float* __restrict__ A, const float* __restrict__ B,
                            uint8_t* __restrict__ Ah8, uint8_t* __restrict__ Bh8,
                            float* __restrict__ sq1, float* __restrict__ sq2) {
  const int lane = threadIdx.x & 63;
  const int wv = threadIdx.x >> 6;
  int row = blockIdx.x * 4 + wv;
  const float* src;
  uint8_t* dst;
  float* sq;
  if (row < N_ROWS) {
    src = A + (size_t)row * KDIM;
    dst = Ah8 + (size_t)row * KDIM;
    sq = sq1 + row;
  } else {
    int r = row - N_ROWS;
    src = B + (size_t)r * KDIM;
    dst = Bh8 + (size_t)r * KDIM;
    sq = sq2 + r;
  }
  const float4* s4 = (const float4*)src;
  float4 v0 = s4[lane * 2];
  float4 v1 = s4[lane * 2 + 1];
  uint32_t w0 = 0, w1 = 0;
  w0 = __builtin_amdgcn_cvt_pk_fp8_f32(v0.x, v0.y, w0, 0);
  w0 = __builtin_amdgcn_cvt_pk_fp8_f32(v0.z, v0.w, w0, 1);
  w1 = __builtin_amdgcn_cvt_pk_fp8_f32(v1.x, v1.y, w1, 0);
  w1 = __builtin_amdgcn_cvt_pk_fp8_f32(v1.z, v1.w, w1, 1);
  uint2 pk = {w0, w1};
  ((uint2*)dst)[lane] = pk;
  float s = v0.x * v0.x + v0.y * v0.y + v0.z * v0.z + v0.w * v0.w
          + v1.x * v1.x + v1.y * v1.y + v1.z * v1.z + v1.w * v1.w;
  #pragma unroll
  for (int off = 32; off; off >>= 1) s += __shfl_down(s, off, 64);
  if (lane == 0) *sq = s;
}

// Kernel 2: fused fp8 GEMM + running-min.
// 2 waves/block; wave wv owns A rows [wv*64, wv*64+64) fully in registers
// (areg[4][4] intx8 = 128 VGPRs, K=512 of fp8). B streams through LDS:
// double-buffered 2 x 8KB phases (64 cols x 128 k), XOR-swizzled 16B chunks
// (col c, slot s holds chunk s ^ (c&7)) -> ds_read_b128 at uniform
// 8 accesses/bank (conflict-free minimum). MFMA: mfma_scale 16x16x128
// f8f6f4 fmt FP8/FP8, unit scales (each lane's 32 contiguous k bytes = one
// MX block). FLOP/LDS-byte = 128 vs R3's 32 (fp8 + 64 rows/wave).
// 1-D grid, chunk = bid & 7 pins each 1MB fp8 B-chunk to one XCD's L2.
__global__ void __launch_bounds__(128, 2)
gemm_min_kernel(const uint8_t* __restrict__ Ah8, const uint8_t* __restrict__ Bh8,
                const float* __restrict__ sq2, float* __restrict__ ws_min) {
  __shared__ __align__(16) uint8_t lsB[2][BNT * BKP];   // 2 x 8 KB

  const int tid = threadIdx.x;
  const int lane = tid & 63;
  const int wv = tid >> 6;       // 0..1
  const int fr = lane & 15;
  const int kg = lane >> 4;      // 0..3
  const int frs = fr & 7;

  const int bid = blockIdx.x;
  const int chunk = bid & 7;
  const int rowBase = (bid >> 3) * BM;
  const int colBase0 = chunk * CHUNK_ROWS;

  // Staging: 8 slots of 1KB per phase (slot = 8 cols x 128 B); wave wv does
  // slots [wv*4, wv*4+4). lane -> col-in-slot = lane>>3, chunk s = lane&7,
  // swizzle key = col&7 = lane>>3.
  const int cis = lane >> 3;                       // col in slot
  const int kofs_st = (((lane & 7) ^ cis) << 4);   // swizzled 16B source chunk

  // ---- Persistent A fragments: areg[i][p] = row (rowBase+wv*64+i*16+fr),
  // k = p*128 + kg*32 .. +32 (32 bytes = 8 VGPRs each; 16 frags = 128 VGPRs).
  intx8 areg[4][4];
  {
    const uint8_t* abase = Ah8 + (size_t)(rowBase + wv * 64 + fr) * KDIM + kg * 32;
    #pragma unroll
    for (int i = 0; i < 4; i++)
      #pragma unroll
      for (int p = 0; p < 4; p++) {
        const uint8_t* ap = abase + (size_t)i * 16 * KDIM + p * BKP;
        intx4 lo = *(const intx4*)ap;
        intx4 hi = *(const intx4*)(ap + 16);
        areg[i][p] = __builtin_shufflevector(lo, hi, 0, 1, 2, 3, 4, 5, 6, 7);
      }
  }

  float runmin[4][4];
  #pragma unroll
  for (int i = 0; i < 4; i++)
    #pragma unroll
    for (int r4 = 0; r4 < 4; r4++) runmin[i][r4] = 3.0e38f;

  // Stage one 64-col x 128-k phase (8 KB): 4 wave-calls per wave.
  #define STAGE_B(buf, cb, kbase_)                                            \
    {                                                                         \
      _Pragma("unroll")                                                       \
      for (int c = 0; c < 4; ++c) {                                           \
        const int slot = wv * 4 + c;                                          \
        async_ld16(Bh8 + (size_t)((cb) + slot * 8 + cis) * KDIM +             \
                       (kbase_) + kofs_st,                                    \
                   (buf) + (slot << 10));                                     \
      }                                                                       \
    }

  STAGE_B(lsB[0], colBase0, 0)
  __syncthreads();

  for (int bt = 0; bt < BT_PER_CHUNK; ++bt) {
    const int colBase = colBase0 + bt * BNT;
    floatx4 acc[4][4];
    #pragma unroll
    for (int i = 0; i < 4; i++)
      #pragma unroll
      for (int j = 0; j < 4; j++) acc[i][j] = (floatx4){0.f, 0.f, 0.f, 0.f};

    #pragma unroll
    for (int p = 0; p < 4; ++p) {
      const uint8_t* cur = lsB[p & 1];
      if (p < 3) {
        STAGE_B(lsB[(p + 1) & 1], colBase, (p + 1) * BKP)
      } else if (bt + 1 < BT_PER_CHUNK) {
        STAGE_B(lsB[0], colBase + BNT, 0)
      }
      // Compute phase p: 16 MFMAs/wave.
      #pragma unroll
      for (int j = 0; j < 4; j++) {
        const uint8_t* bp = cur + (j * 16 + fr) * BKP;
        intx4 lo = *(const intx4*)(bp + ((((kg << 1)) ^ frs) << 4));
        intx4 hi = *(const intx4*)(bp + ((((kg << 1) | 1) ^ frs) << 4));
        intx8 bv = __builtin_shufflevector(lo, hi, 0, 1, 2, 3, 4, 5, 6, 7);
        #pragma unroll
        for (int i = 0; i < 4; i++)
          acc[i][j] = __builtin_amdgcn_mfma_scale_f32_16x16x128_f8f6f4(
              areg[i][p], bv, acc[i][j], 0, 0,
              0, UNIT_SCALE, 0, UNIT_SCALE);
      }
      __syncthreads();
    }

    // Epilogue: cand = sq2[col] - 2*inner -> per-row running min.
    // C frag: col = j*16 + fr, row = wv*64 + i*16 + kg*4 + reg.
    #pragma unroll
    for (int j = 0; j < 4; j++) {
      const float s2 = sq2[colBase + j * 16 + fr];
      #pragma unroll
      for (int i = 0; i < 4; i++)
        #pragma unroll
        for (int r4 = 0; r4 < 4; r4++) {
          const float cand = fmaf(-2.f, acc[i][j][r4], s2);
          runmin[i][r4] = fminf(runmin[i][r4], cand);
        }
    }
  }

  // Min over the 16 columns per lane row-group: butterfly on lane bits 0..3.
  #pragma unroll
  for (int i = 0; i < 4; i++)
    #pragma unroll
    for (int r4 = 0; r4 < 4; r4++) {
      float v = runmin[i][r4];
      v = fminf(v, __shfl_xor(v, 1, 64));
      v = fminf(v, __shfl_xor(v, 2, 64));
      v = fminf(v, __shfl_xor(v, 4, 64));
      v = fminf(v, __shfl_xor(v, 8, 64));
      runmin[i][r4] = v;
    }

  if (fr == 0) {
    #pragma unroll
    for (int i = 0; i < 4; i++)
      #pragma unroll
      for (int r4 = 0; r4 < 4; r4++) {
        const int lrow = wv * 64 + i * 16 + kg * 4 + r4;
        ws_min[(size_t)chunk * N_ROWS + rowBase + lrow] = runmin[i][r4];
      }
  }
}

// Kernel 3a: per-row min across chunks + sqrt/relu, 64-block partial sums.
__global__ void partial_kernel(const float* __restrict__ ws_min,
                               const float* __restrict__ sq1,
                               float* __restrict__ part) {
  const int r = blockIdx.x * 256 + threadIdx.x;
  float m = ws_min[r];
  #pragma unroll
  for (int c = 1; c < NCHUNK; c++) m = fminf(m, ws_min[(size_t)c * N_ROWS + r]);
  float d2 = sq1[r] + m;
  d2 = d2 > 0.f ? d2 : 0.f;
  float v = sqrtf(d2) - 0.1f;
  float s = v > 0.f ? v : 0.f;
  #pragma unroll
  for (int off = 32; off; off >>= 1) s += __shfl_down(s, off, 64);
  __shared__ float ps[4];
  if ((threadIdx.x & 63) == 0) ps[threadIdx.x >> 6] = s;
  __syncthreads();
  if (threadIdx.x == 0) part[blockIdx.x] = ps[0] + ps[1] + ps[2] + ps[3];
}

// Kernel 3b: combine 64 partials.
__global__ void final_kernel(const float* __restrict__ part, float* __restrict__ out) {
  float s = part[threadIdx.x];
  #pragma unroll
  for (int off = 32; off; off >>= 1) s += __shfl_down(s, off, 64);
  if (threadIdx.x == 0) out[0] = s / (float)N_ROWS;
}

extern "C" void kernel_launch(void* const* d_in, const int* in_sizes, int n_in,
                              void* d_out, int out_size, void* d_ws, size_t ws_size,
                              hipStream_t stream) {
  const float* A = (const float*)d_in[0];
  const float* B = (const float*)d_in[1];
  char* ws = (char*)d_ws;
  const size_t fp8Bytes = (size_t)N_ROWS * KDIM;   // 8 MiB each
  uint8_t* Ah8 = (uint8_t*)ws;
  uint8_t* Bh8 = (uint8_t*)(ws + fp8Bytes);
  float* sq1 = (float*)(ws + 2 * fp8Bytes);
  float* sq2 = sq1 + N_ROWS;
  float* ws_min = sq2 + M_ROWS;
  float* part = ws_min + (size_t)NCHUNK * N_ROWS;

  conv_kernel<<<dim3((N_ROWS + M_ROWS) / 4), dim3(256), 0, stream>>>(A, B, Ah8, Bh8, sq1, sq2);
  gemm_min_kernel<<<dim3((N_ROWS / BM) * NCHUNK), dim3(128), 0, stream>>>(Ah8, Bh8, sq2, ws_min);
  partial_kernel<<<dim3(64), dim3(256), 0, stream>>>(ws_min, sq1, part);
  final_kernel<<<dim3(1), dim3(64), 0, stream>>>(part, (float*)d_out);
}